// Round 7
// baseline (301.555 us; speedup 1.0000x reference)
//
#include <hip/hip_runtime.h>
#include <hip/hip_bf16.h>
#include <hip/hip_fp16.h>

#define N_NODES 50000
#define N_EDGES 800000
#define NTILES 3125        // N_NODES / 16
#define SCAN_NB 196        // ceil(N_NODES / 256)
#define W_TOTAL 57344      // packed bf16 weight elements
#define WB 224             // weight-pack blocks
#define SRC_PAD 512        // sentinel tail on srcA
#define CLS_BLOCKS 1024    // classed edge-walk blocks
#define CLS_STRIDE (128 * 256)
#define CLS_RANGE 6250     // dst nodes per class (8 * 6250 = 50000)
#define TB 782             // layer1/dense MFMA blocks (4 waves each)
#define NBIN 64            // degree bins for row sorting (clamped)

typedef __attribute__((ext_vector_type(8))) short bf16x8;          // MFMA A/B frag
typedef __attribute__((ext_vector_type(4))) float f32x4;           // MFMA C/D frag
typedef __attribute__((ext_vector_type(8))) unsigned short u16x8;  // 16B store

__device__ inline unsigned short f2bf(float f) {  // round-to-nearest-even
    unsigned int x = __float_as_uint(f);
    unsigned int r = (x + 0x7FFF + ((x >> 16) & 1)) >> 16;
    return (unsigned short)r;
}
__device__ inline float2 h2f2(unsigned int u) {   // packed half2 -> float2
    __half2 h = *(__half2*)&u;
    return make_float2(__low2float(h), __high2float(h));
}

// ---------------------------------------------------------------------------
// fused: XCD-classed degree count (blocks [0,CLS_BLOCKS)) + weight pack (rest).
// First pack block also zeroes the degree histogram (read only by scan1).
__global__ __launch_bounds__(256) void count_pack_kernel(
    const int* __restrict__ dst, int* __restrict__ degi,
    const float* W1, const float* W2, const float* A2a, const float* A2b,
    const float* W3, const float* A3a, const float* A3b,
    const float* W4, const float* A4a, const float* A4b,
    unsigned short* __restrict__ wp, int* __restrict__ dhist) {
    if (blockIdx.x < CLS_BLOCKS) {
        int cls = blockIdx.x & 7;
        int k = blockIdx.x >> 3;
        int lo = cls * CLS_RANGE, hi = lo + CLS_RANGE;
        for (int e = k * 256 + (int)threadIdx.x; e < N_EDGES; e += CLS_STRIDE) {
            int d = dst[e];
            if (d >= lo && d < hi) atomicAdd(&degi[d], 1);
        }
    } else {
        if (blockIdx.x == CLS_BLOCKS && threadIdx.x < NBIN) dhist[threadIdx.x] = 0;
        int i = (blockIdx.x - CLS_BLOCKS) * 256 + threadIdx.x;
        if (i >= W_TOTAL) return;
        float v;
        if (i < 8192)       v = W1[i];
        else if (i < 16384) v = W2[i - 8192];
        else if (i < 20480) v = A2a[i - 16384];
        else if (i < 24576) v = A2b[i - 20480];
        else if (i < 32768) v = W3[i - 24576];
        else if (i < 36864) v = A3a[i - 32768];
        else if (i < 40960) v = A3b[i - 36864];
        else if (i < 49152) v = W4[i - 40960];
        else if (i < 53248) v = A4a[i - 49152];
        else                v = A4b[i - 53248];
        wp[i] = f2bf(v);
    }
}

// scan phase 1: per-256-chunk inclusive scan + chunk totals; isq = rsqrt(max(deg,1));
// also per-block LDS degree histogram -> global dhist.
__global__ __launch_bounds__(256) void scan1_kernel(const int* __restrict__ degi,
                                                    int* __restrict__ incl,
                                                    int* __restrict__ partial,
                                                    float* __restrict__ isq,
                                                    int* __restrict__ dhist) {
    __shared__ int s[256];
    __shared__ int lh[NBIN];
    int tid = threadIdx.x;
    if (tid < NBIN) lh[tid] = 0;
    __syncthreads();
    int gid = blockIdx.x * 256 + tid;
    int v = (gid < N_NODES) ? degi[gid] : 0;
    if (gid < N_NODES) {
        isq[gid] = rsqrtf(fmaxf((float)v, 1.0f));
        atomicAdd(&lh[min(v, NBIN - 1)], 1);
    }
    s[tid] = v;
    __syncthreads();
    for (int off = 1; off < 256; off <<= 1) {
        int t = (tid >= off) ? s[tid - off] : 0;
        __syncthreads();
        s[tid] += t;
        __syncthreads();
    }
    if (gid < N_NODES) incl[gid] = s[tid];
    if (tid == 255) partial[blockIdx.x] = s[255];
    if (tid < NBIN && lh[tid] > 0) atomicAdd(&dhist[tid], lh[tid]);
}

// scan phase 2 (one block): exclusive scan of chunk totals + srcA sentinel init
// + exclusive scan of the degree histogram -> dcur (bin cursors).
__global__ __launch_bounds__(256) void scan2_kernel(int* __restrict__ partial,
                                                    int* __restrict__ srcA,
                                                    const int* __restrict__ dhist,
                                                    int* __restrict__ dcur) {
    __shared__ int s[256];
    int tid = threadIdx.x;
    int v = (tid < SCAN_NB) ? partial[tid] : 0;
    s[tid] = v;
    __syncthreads();
    for (int off = 1; off < 256; off <<= 1) {
        int t = (tid >= off) ? s[tid - off] : 0;
        __syncthreads();
        s[tid] += t;
        __syncthreads();
    }
    if (tid < SCAN_NB) partial[tid] = s[tid] - v;  // exclusive
    srcA[N_EDGES + tid] = 0;                       // sentinel tail (node 0)
    srcA[N_EDGES + 256 + tid] = 0;
    __syncthreads();
    int hv = (tid < NBIN) ? dhist[tid] : 0;
    s[tid] = hv;
    __syncthreads();
    for (int off = 1; off < 256; off <<= 1) {
        int t = (tid >= off) ? s[tid - off] : 0;
        __syncthreads();
        s[tid] += t;
        __syncthreads();
    }
    if (tid < NBIN) dcur[tid] = s[tid] - hv;       // exclusive bin base
}

// scan phase 3: rowptr (exclusive) + cursor copy + degree-sorted rowOrder
// (per-block LDS histogram -> one global reservation per bin per block).
__global__ __launch_bounds__(256) void scan3_kernel(const int* __restrict__ incl,
                                                    const int* __restrict__ partial,
                                                    const int* __restrict__ degi,
                                                    int* __restrict__ rowptr,
                                                    int* __restrict__ cursor,
                                                    int* __restrict__ dcur,
                                                    int* __restrict__ rowOrder) {
    __shared__ int lh[NBIN];
    __shared__ int lbase[NBIN];
    int tid = threadIdx.x;
    if (tid < NBIN) lh[tid] = 0;
    __syncthreads();
    int gid = blockIdx.x * 256 + tid;
    int bin = 0, lpos = 0;
    if (gid < N_NODES) {
        int dv = degi[gid];
        int excl = partial[blockIdx.x] + incl[gid] - dv;
        rowptr[gid] = excl;
        cursor[gid] = excl;
        bin = min(dv, NBIN - 1);
        lpos = atomicAdd(&lh[bin], 1);
    }
    __syncthreads();
    if (tid < NBIN && lh[tid] > 0) lbase[tid] = atomicAdd(&dcur[tid], lh[tid]);
    __syncthreads();
    if (gid < N_NODES) rowOrder[lbase[bin] + lpos] = gid;
    if (gid == 0) rowptr[N_NODES] = N_EDGES;
}

// ---------------------------------------------------------------------------
// fused layer1 + classed scatter.
__global__ __launch_bounds__(256) void layer1_scatter(const float* __restrict__ x,
                                                      const unsigned short* __restrict__ w1p,
                                                      const float* __restrict__ b1,
                                                      const float* __restrict__ isq,
                                                      unsigned short* __restrict__ outh,
                                                      __half* __restrict__ outs,
                                                      const int* __restrict__ src,
                                                      const int* __restrict__ dst,
                                                      int* __restrict__ cursor,
                                                      int* __restrict__ srcA) {
    if (blockIdx.x >= TB) {
        int cb = blockIdx.x - TB;
        int cls = cb & 7;
        int k = cb >> 3;
        int lo = cls * CLS_RANGE, hi = lo + CLS_RANGE;
        for (int e = k * 256 + (int)threadIdx.x; e < N_EDGES; e += CLS_STRIDE) {
            int d = dst[e];
            if (d >= lo && d < hi) {
                int pos = atomicAdd(&cursor[d], 1);
                srcA[pos] = src[e];
            }
        }
        return;
    }

    int wave = (blockIdx.x * 256 + threadIdx.x) >> 6;
    if (wave >= NTILES) return;
    int lane = threadIdx.x & 63;
    int r16 = lane & 15, quad = lane >> 4;
    int base = wave * 16;

    bf16x8 a[4];
    const float* xr = x + (size_t)(base + r16) * 128 + quad * 8;
#pragma unroll
    for (int kb = 0; kb < 4; kb++) {
        float4 f0 = *(const float4*)(xr + kb * 32);
        float4 f1 = *(const float4*)(xr + kb * 32 + 4);
        bf16x8 v;
        v[0] = (short)f2bf(f0.x); v[1] = (short)f2bf(f0.y);
        v[2] = (short)f2bf(f0.z); v[3] = (short)f2bf(f0.w);
        v[4] = (short)f2bf(f1.x); v[5] = (short)f2bf(f1.y);
        v[6] = (short)f2bf(f1.z); v[7] = (short)f2bf(f1.w);
        a[kb] = v;
    }

    float isq4[4];
#pragma unroll
    for (int r = 0; r < 4; r++) isq4[r] = isq[base + quad * 4 + r];

#pragma unroll
    for (int jt = 0; jt < 4; jt++) {
        f32x4 acc = {0.f, 0.f, 0.f, 0.f};
        const unsigned short* wr = w1p + (size_t)(jt * 16 + r16) * 128 + quad * 8;
#pragma unroll
        for (int kb = 0; kb < 4; kb++) {
            bf16x8 b = *(const bf16x8*)(wr + kb * 32);
            acc = __builtin_amdgcn_mfma_f32_16x16x32_bf16(a[kb], b, acc, 0, 0, 0);
        }
        int col = jt * 16 + r16;
        float bias = b1[col];
#pragma unroll
        for (int r = 0; r < 4; r++) {
            int row = base + quad * 4 + r;
            float v = fmaxf(acc[r] + bias, 0.f);
            outh[(size_t)row * 64 + col] = f2bf(v);
            outs[(size_t)row * 64 + col] = __float2half(v * isq4[r]);
        }
    }
}

// ---------------------------------------------------------------------------
// conv (CSR, 8 rows/wave, degree-sorted): out[d,:] = isq[d]*sum hs[src,:].
// Eighth-wave per dst row (rows of ~equal degree via rowOrder); lane covers
// 8 feats (uint4 = one 16B gather) -> one gather instruction serves 8 edges;
// 4-deep unroll keeps 4 independent gathers in flight per lane.
__global__ __launch_bounds__(256) void conv_csr8(const __half* __restrict__ hs,
                                                 const int* __restrict__ rowptr,
                                                 const int* __restrict__ srcA,
                                                 const int* __restrict__ rowOrder,
                                                 const float* __restrict__ isq,
                                                 unsigned short* __restrict__ out) {
    int wave = (blockIdx.x * 256 + threadIdx.x) >> 6;
    if (wave >= N_NODES / 8) return;   // 6250 waves
    int lane = threadIdx.x & 63;
    int e8 = lane >> 3, fl = lane & 7;
    int d = rowOrder[wave * 8 + e8];
    int b = rowptr[d];
    int cnt = rowptr[d + 1] - b;

    const unsigned int* hsp = (const unsigned int*)hs;  // hs row = 32 uints
    float acc[8];
#pragma unroll
    for (int k = 0; k < 8; k++) acc[k] = 0.f;

    for (int i = 0; i < cnt; i += 4) {
#pragma unroll
        for (int u = 0; u < 4; u++) {
            int j = i + u;
            int s = srcA[b + j];                        // sentinel-safe
            uint4 raw = *(const uint4*)(hsp + (size_t)s * 32 + fl * 4);
            unsigned int msk = (j < cnt) ? 0xFFFFFFFFu : 0u;
            float2 f0 = h2f2(raw.x & msk);
            float2 f1 = h2f2(raw.y & msk);
            float2 f2 = h2f2(raw.z & msk);
            float2 f3 = h2f2(raw.w & msk);
            acc[0] += f0.x; acc[1] += f0.y; acc[2] += f1.x; acc[3] += f1.y;
            acc[4] += f2.x; acc[5] += f2.y; acc[6] += f3.x; acc[7] += f3.y;
        }
    }
    float sc = isq[d];
    u16x8 o;
#pragma unroll
    for (int k = 0; k < 8; k++) o[k] = f2bf(acc[k] * sc);
    *(u16x8*)(out + (size_t)d * 64 + fl * 8) = o;
}

// ---------------------------------------------------------------------------
// dense block: out = relu( [h,conv]@W^T + (h@Aa^T)*(h@Ab^T) )
__global__ __launch_bounds__(256) void dense_mfma(const unsigned short* __restrict__ h,
                                                  const unsigned short* __restrict__ cv,
                                                  const unsigned short* __restrict__ wp,
                                                  const unsigned short* __restrict__ aap,
                                                  const unsigned short* __restrict__ abp,
                                                  const float* __restrict__ isq,
                                                  unsigned short* __restrict__ outh,
                                                  __half* __restrict__ outs,
                                                  float* __restrict__ outf,
                                                  int finalLayer) {
    int wave = (blockIdx.x * 256 + threadIdx.x) >> 6;
    if (wave >= NTILES) return;
    int lane = threadIdx.x & 63;
    int r16 = lane & 15, quad = lane >> 4;
    int base = wave * 16;

    const unsigned short* hr = h + (size_t)(base + r16) * 64 + quad * 8;
    const unsigned short* cr = cv + (size_t)(base + r16) * 64 + quad * 8;
    bf16x8 ha0 = *(const bf16x8*)(hr);
    bf16x8 ha1 = *(const bf16x8*)(hr + 32);
    bf16x8 ca0 = *(const bf16x8*)(cr);
    bf16x8 ca1 = *(const bf16x8*)(cr + 32);

    float isq4[4];
    if (!finalLayer) {
#pragma unroll
        for (int r = 0; r < 4; r++) isq4[r] = isq[base + quad * 4 + r];
    }

#pragma unroll
    for (int jt = 0; jt < 4; jt++) {
        const unsigned short* wr = wp + (size_t)(jt * 16 + r16) * 128 + quad * 8;
        const unsigned short* ar = aap + (size_t)(jt * 16 + r16) * 64 + quad * 8;
        const unsigned short* br = abp + (size_t)(jt * 16 + r16) * 64 + quad * 8;
        f32x4 P = {0.f, 0.f, 0.f, 0.f};
        f32x4 Q = {0.f, 0.f, 0.f, 0.f};
        f32x4 R = {0.f, 0.f, 0.f, 0.f};
        P = __builtin_amdgcn_mfma_f32_16x16x32_bf16(ha0, *(const bf16x8*)(wr), P, 0, 0, 0);
        P = __builtin_amdgcn_mfma_f32_16x16x32_bf16(ha1, *(const bf16x8*)(wr + 32), P, 0, 0, 0);
        P = __builtin_amdgcn_mfma_f32_16x16x32_bf16(ca0, *(const bf16x8*)(wr + 64), P, 0, 0, 0);
        P = __builtin_amdgcn_mfma_f32_16x16x32_bf16(ca1, *(const bf16x8*)(wr + 96), P, 0, 0, 0);
        Q = __builtin_amdgcn_mfma_f32_16x16x32_bf16(ha0, *(const bf16x8*)(ar), Q, 0, 0, 0);
        Q = __builtin_amdgcn_mfma_f32_16x16x32_bf16(ha1, *(const bf16x8*)(ar + 32), Q, 0, 0, 0);
        R = __builtin_amdgcn_mfma_f32_16x16x32_bf16(ha0, *(const bf16x8*)(br), R, 0, 0, 0);
        R = __builtin_amdgcn_mfma_f32_16x16x32_bf16(ha1, *(const bf16x8*)(br + 32), R, 0, 0, 0);
        int col = jt * 16 + r16;
#pragma unroll
        for (int r = 0; r < 4; r++) {
            int row = base + quad * 4 + r;
            float v = fmaxf(P[r] + Q[r] * R[r], 0.f);
            if (finalLayer) {
                outf[(size_t)row * 64 + col] = v;
            } else {
                outh[(size_t)row * 64 + col] = f2bf(v);
                outs[(size_t)row * 64 + col] = __float2half(v * isq4[r]);
            }
        }
    }
}

// ---------------------------------------------------------------------------
extern "C" void kernel_launch(void* const* d_in, const int* in_sizes, int n_in,
                              void* d_out, int out_size, void* d_ws, size_t ws_size,
                              hipStream_t stream) {
    const float* x = (const float*)d_in[0];
    const int* edges = (const int*)d_in[1];
    const float* W1 = (const float*)d_in[2];
    const float* b1 = (const float*)d_in[3];
    const float* W2 = (const float*)d_in[4];
    const float* A2a = (const float*)d_in[5];
    const float* A2b = (const float*)d_in[6];
    const float* W3 = (const float*)d_in[7];
    const float* A3a = (const float*)d_in[8];
    const float* A3b = (const float*)d_in[9];
    const float* W4 = (const float*)d_in[10];
    const float* A4a = (const float*)d_in[11];
    const float* A4b = (const float*)d_in[12];
    float* out = (float*)d_out;

    const int* src = edges;
    const int* dst = edges + N_EDGES;

    char* p = (char*)d_ws;
    auto alloc = [&](size_t bytes) {
        char* r = p;
        p += (bytes + 255) & ~(size_t)255;
        return r;
    };
    int* degi             = (int*)alloc(N_NODES * 4);
    int* incl             = (int*)alloc(N_NODES * 4);
    int* partial          = (int*)alloc(256 * 4);
    float* isq            = (float*)alloc(N_NODES * 4);
    int* rowptr           = (int*)alloc((N_NODES + 1) * 4);
    int* cursor           = (int*)alloc(N_NODES * 4);
    int* srcA             = (int*)alloc((N_EDGES + SRC_PAD) * 4);
    int* dhist            = (int*)alloc(NBIN * 4);
    int* dcur             = (int*)alloc(NBIN * 4);
    int* rowOrder         = (int*)alloc(N_NODES * 4);
    unsigned short* wpAll = (unsigned short*)alloc(W_TOTAL * 2);
    unsigned short* Ah    = (unsigned short*)alloc((size_t)N_NODES * 64 * 2);
    __half* As            = (__half*)alloc((size_t)N_NODES * 64 * 2);
    unsigned short* Bh    = (unsigned short*)alloc((size_t)N_NODES * 64 * 2);
    unsigned short* C     = (unsigned short*)alloc((size_t)N_NODES * 64 * 2);

    const unsigned short* W1p  = wpAll;
    const unsigned short* W2p  = wpAll + 8192;
    const unsigned short* A2ap = wpAll + 16384;
    const unsigned short* A2bp = wpAll + 20480;
    const unsigned short* W3p  = wpAll + 24576;
    const unsigned short* A3ap = wpAll + 32768;
    const unsigned short* A3bp = wpAll + 36864;
    const unsigned short* W4p  = wpAll + 40960;
    const unsigned short* A4ap = wpAll + 49152;
    const unsigned short* A4bp = wpAll + 53248;

    const int CVB = (N_NODES / 8 + 3) / 4;    // conv blocks: 6250 waves / 4

    // ---- CSR build + weight pack ----
    hipMemsetAsync(degi, 0, N_NODES * 4, stream);
    count_pack_kernel<<<CLS_BLOCKS + WB, 256, 0, stream>>>(dst, degi, W1, W2, A2a, A2b,
                                                           W3, A3a, A3b, W4, A4a, A4b,
                                                           wpAll, dhist);
    scan1_kernel<<<SCAN_NB, 256, 0, stream>>>(degi, incl, partial, isq, dhist);
    scan2_kernel<<<1, 256, 0, stream>>>(partial, srcA, dhist, dcur);
    scan3_kernel<<<SCAN_NB, 256, 0, stream>>>(incl, partial, degi, rowptr, cursor,
                                              dcur, rowOrder);

    // ---- layer 1 (MFMA) + classed scatter, fused ----
    layer1_scatter<<<TB + CLS_BLOCKS, 256, 0, stream>>>(x, W1p, b1, isq, Ah, As,
                                                        src, dst, cursor, srcA);

    // ---- block 2 ----
    conv_csr8<<<CVB, 256, 0, stream>>>(As, rowptr, srcA, rowOrder, isq, C);
    dense_mfma<<<TB, 256, 0, stream>>>(Ah, C, W2p, A2ap, A2bp, isq, Bh, As, nullptr, 0);

    // ---- block 3 ----
    conv_csr8<<<CVB, 256, 0, stream>>>(As, rowptr, srcA, rowOrder, isq, C);
    dense_mfma<<<TB, 256, 0, stream>>>(Bh, C, W3p, A3ap, A3bp, isq, Ah, As, nullptr, 0);

    // ---- block 4 -> d_out (fp32) ----
    conv_csr8<<<CVB, 256, 0, stream>>>(As, rowptr, srcA, rowOrder, isq, C);
    dense_mfma<<<TB, 256, 0, stream>>>(Ah, C, W4p, A4ap, A4bp, isq, nullptr, nullptr, out, 1);
}

// Round 8
// 288.152 us; speedup vs baseline: 1.0465x; 1.0465x over previous
//
#include <hip/hip_runtime.h>
#include <hip/hip_bf16.h>
#include <hip/hip_fp16.h>

#define N_NODES 50000
#define N_EDGES 800000
#define NTILES 3125        // N_NODES / 16
#define SCAN_NB 196        // ceil(N_NODES / 256)
#define W_TOTAL 57344      // packed bf16 weight elements
#define WB 224             // weight-pack blocks
#define SRC_PAD 512        // sentinel tail on srcA
#define CLS_BLOCKS 1024    // classed edge-walk blocks
#define CLS_STRIDE (128 * 256)
#define CLS_RANGE 6250     // dst nodes per class (8 * 6250 = 50000)
#define TB 782             // layer1 MFMA blocks (4 waves each)
#define FB 782             // fused conv+dense blocks (64 rows each)

typedef __attribute__((ext_vector_type(8))) short bf16x8;          // MFMA A/B frag
typedef __attribute__((ext_vector_type(4))) float f32x4;           // MFMA C/D frag
typedef __attribute__((ext_vector_type(8))) unsigned short u16x8;  // 16B store

__device__ inline unsigned short f2bf(float f) {  // round-to-nearest-even
    unsigned int x = __float_as_uint(f);
    unsigned int r = (x + 0x7FFF + ((x >> 16) & 1)) >> 16;
    return (unsigned short)r;
}
__device__ inline float2 h2f2(unsigned int u) {   // packed half2 -> float2
    __half2 h = *(__half2*)&u;
    return make_float2(__low2float(h), __high2float(h));
}

// ---------------------------------------------------------------------------
// fused: XCD-classed degree count (blocks [0,CLS_BLOCKS)) + weight pack (rest).
__global__ __launch_bounds__(256) void count_pack_kernel(
    const int* __restrict__ dst, int* __restrict__ degi,
    const float* W1, const float* W2, const float* A2a, const float* A2b,
    const float* W3, const float* A3a, const float* A3b,
    const float* W4, const float* A4a, const float* A4b,
    unsigned short* __restrict__ wp) {
    if (blockIdx.x < CLS_BLOCKS) {
        int cls = blockIdx.x & 7;
        int k = blockIdx.x >> 3;
        int lo = cls * CLS_RANGE, hi = lo + CLS_RANGE;
        for (int e = k * 256 + (int)threadIdx.x; e < N_EDGES; e += CLS_STRIDE) {
            int d = dst[e];
            if (d >= lo && d < hi) atomicAdd(&degi[d], 1);
        }
    } else {
        int i = (blockIdx.x - CLS_BLOCKS) * 256 + threadIdx.x;
        if (i >= W_TOTAL) return;
        float v;
        if (i < 8192)       v = W1[i];
        else if (i < 16384) v = W2[i - 8192];
        else if (i < 20480) v = A2a[i - 16384];
        else if (i < 24576) v = A2b[i - 20480];
        else if (i < 32768) v = W3[i - 24576];
        else if (i < 36864) v = A3a[i - 32768];
        else if (i < 40960) v = A3b[i - 36864];
        else if (i < 49152) v = W4[i - 40960];
        else if (i < 53248) v = A4a[i - 49152];
        else                v = A4b[i - 53248];
        wp[i] = f2bf(v);
    }
}

// scan phase 1: per-256-chunk inclusive scan + chunk totals; isq = rsqrt(max(deg,1))
__global__ __launch_bounds__(256) void scan1_kernel(const int* __restrict__ degi,
                                                    int* __restrict__ incl,
                                                    int* __restrict__ partial,
                                                    float* __restrict__ isq) {
    __shared__ int s[256];
    int tid = threadIdx.x;
    int gid = blockIdx.x * 256 + tid;
    int v = (gid < N_NODES) ? degi[gid] : 0;
    if (gid < N_NODES) isq[gid] = rsqrtf(fmaxf((float)v, 1.0f));
    s[tid] = v;
    __syncthreads();
    for (int off = 1; off < 256; off <<= 1) {
        int t = (tid >= off) ? s[tid - off] : 0;
        __syncthreads();
        s[tid] += t;
        __syncthreads();
    }
    if (gid < N_NODES) incl[gid] = s[tid];
    if (tid == 255) partial[blockIdx.x] = s[255];
}

// scan phase 2 (one block): exclusive scan of chunk totals + srcA sentinel init
__global__ __launch_bounds__(256) void scan2_kernel(int* __restrict__ partial,
                                                    int* __restrict__ srcA) {
    __shared__ int s[256];
    int tid = threadIdx.x;
    int v = (tid < SCAN_NB) ? partial[tid] : 0;
    s[tid] = v;
    __syncthreads();
    for (int off = 1; off < 256; off <<= 1) {
        int t = (tid >= off) ? s[tid - off] : 0;
        __syncthreads();
        s[tid] += t;
        __syncthreads();
    }
    if (tid < SCAN_NB) partial[tid] = s[tid] - v;  // exclusive
    srcA[N_EDGES + tid] = 0;                       // sentinel tail (node 0)
    srcA[N_EDGES + 256 + tid] = 0;
}

// scan phase 3: rowptr (exclusive) + cursor copy
__global__ __launch_bounds__(256) void scan3_kernel(const int* __restrict__ incl,
                                                    const int* __restrict__ partial,
                                                    const int* __restrict__ degi,
                                                    int* __restrict__ rowptr,
                                                    int* __restrict__ cursor) {
    int gid = blockIdx.x * 256 + threadIdx.x;
    if (gid < N_NODES) {
        int excl = partial[blockIdx.x] + incl[gid] - degi[gid];
        rowptr[gid] = excl;
        cursor[gid] = excl;
    }
    if (gid == 0) rowptr[N_NODES] = N_EDGES;
}

// ---------------------------------------------------------------------------
// fused layer1 + classed scatter.
__global__ __launch_bounds__(256) void layer1_scatter(const float* __restrict__ x,
                                                      const unsigned short* __restrict__ w1p,
                                                      const float* __restrict__ b1,
                                                      const float* __restrict__ isq,
                                                      unsigned short* __restrict__ outh,
                                                      __half* __restrict__ outs,
                                                      const int* __restrict__ src,
                                                      const int* __restrict__ dst,
                                                      int* __restrict__ cursor,
                                                      int* __restrict__ srcA) {
    if (blockIdx.x >= TB) {
        int cb = blockIdx.x - TB;
        int cls = cb & 7;
        int k = cb >> 3;
        int lo = cls * CLS_RANGE, hi = lo + CLS_RANGE;
        for (int e = k * 256 + (int)threadIdx.x; e < N_EDGES; e += CLS_STRIDE) {
            int d = dst[e];
            if (d >= lo && d < hi) {
                int pos = atomicAdd(&cursor[d], 1);
                srcA[pos] = src[e];
            }
        }
        return;
    }

    int wave = (blockIdx.x * 256 + threadIdx.x) >> 6;
    if (wave >= NTILES) return;
    int lane = threadIdx.x & 63;
    int r16 = lane & 15, quad = lane >> 4;
    int base = wave * 16;

    bf16x8 a[4];
    const float* xr = x + (size_t)(base + r16) * 128 + quad * 8;
#pragma unroll
    for (int kb = 0; kb < 4; kb++) {
        float4 f0 = *(const float4*)(xr + kb * 32);
        float4 f1 = *(const float4*)(xr + kb * 32 + 4);
        bf16x8 v;
        v[0] = (short)f2bf(f0.x); v[1] = (short)f2bf(f0.y);
        v[2] = (short)f2bf(f0.z); v[3] = (short)f2bf(f0.w);
        v[4] = (short)f2bf(f1.x); v[5] = (short)f2bf(f1.y);
        v[6] = (short)f2bf(f1.z); v[7] = (short)f2bf(f1.w);
        a[kb] = v;
    }

    float isq4[4];
#pragma unroll
    for (int r = 0; r < 4; r++) isq4[r] = isq[base + quad * 4 + r];

#pragma unroll
    for (int jt = 0; jt < 4; jt++) {
        f32x4 acc = {0.f, 0.f, 0.f, 0.f};
        const unsigned short* wr = w1p + (size_t)(jt * 16 + r16) * 128 + quad * 8;
#pragma unroll
        for (int kb = 0; kb < 4; kb++) {
            bf16x8 b = *(const bf16x8*)(wr + kb * 32);
            acc = __builtin_amdgcn_mfma_f32_16x16x32_bf16(a[kb], b, acc, 0, 0, 0);
        }
        int col = jt * 16 + r16;
        float bias = b1[col];
#pragma unroll
        for (int r = 0; r < 4; r++) {
            int row = base + quad * 4 + r;
            float v = fmaxf(acc[r] + bias, 0.f);
            outh[(size_t)row * 64 + col] = f2bf(v);
            outs[(size_t)row * 64 + col] = __float2half(v * isq4[r]);
        }
    }
}

// ---------------------------------------------------------------------------
// FUSED conv + dense, one block = 64 rows (4 MFMA tiles).
// Phase 1 (conv): wave wv computes conv for rows [wv*16, wv*16+16) of the
//   block in 2 groups of 8 rows (8 feat-lanes x uint4 = 16B gather, one
//   instruction serves 8 edges); result -> LDS bf16 [64][64].
// Phase 2 (dense): wave wv runs MFMA tile wv; conv A-frags read from LDS,
//   h A-frags from global. Epilogue as before.
__global__ __launch_bounds__(256) void conv_dense(const unsigned short* __restrict__ h,
                                                  const __half* __restrict__ hs,
                                                  const int* __restrict__ rowptr,
                                                  const int* __restrict__ srcA,
                                                  const float* __restrict__ isq,
                                                  const unsigned short* __restrict__ wp,
                                                  const unsigned short* __restrict__ aap,
                                                  const unsigned short* __restrict__ abp,
                                                  unsigned short* __restrict__ outh,
                                                  __half* __restrict__ outs,
                                                  float* __restrict__ outf,
                                                  int finalLayer) {
    __shared__ unsigned short clds[64][64];   // conv result (bf16), 8 KB

    int tid = threadIdx.x;
    int wv = tid >> 6;
    int lane = tid & 63;
    int blockBase = blockIdx.x * 64;

    // ---- phase 1: conv for this block's 64 rows ----
    {
        int e8 = lane >> 3, fl = lane & 7;
        const unsigned int* hsp = (const unsigned int*)hs;  // hs row = 32 uints
#pragma unroll
        for (int g = 0; g < 2; g++) {
            int lrow = wv * 16 + g * 8 + e8;
            int row = blockBase + lrow;
            if (row < N_NODES) {
                int b = rowptr[row];
                int cnt = rowptr[row + 1] - b;
                float acc[8];
#pragma unroll
                for (int k = 0; k < 8; k++) acc[k] = 0.f;
                for (int i = 0; i < cnt; i += 4) {
#pragma unroll
                    for (int u = 0; u < 4; u++) {
                        int j = i + u;
                        int s = srcA[b + j];                 // sentinel-safe
                        uint4 raw = *(const uint4*)(hsp + (size_t)s * 32 + fl * 4);
                        unsigned int msk = (j < cnt) ? 0xFFFFFFFFu : 0u;
                        float2 f0 = h2f2(raw.x & msk);
                        float2 f1 = h2f2(raw.y & msk);
                        float2 f2 = h2f2(raw.z & msk);
                        float2 f3 = h2f2(raw.w & msk);
                        acc[0] += f0.x; acc[1] += f0.y; acc[2] += f1.x; acc[3] += f1.y;
                        acc[4] += f2.x; acc[5] += f2.y; acc[6] += f3.x; acc[7] += f3.y;
                    }
                }
                float sc = isq[row];
                u16x8 o;
#pragma unroll
                for (int k = 0; k < 8; k++) o[k] = f2bf(acc[k] * sc);
                *(u16x8*)(&clds[lrow][fl * 8]) = o;
            }
        }
    }
    __syncthreads();

    // ---- phase 2: dense MFMA tile wv (16 rows) ----
    int r16 = lane & 15, quad = lane >> 4;
    int base = blockBase + wv * 16;
    if (base >= N_NODES) return;

    const unsigned short* hr = h + (size_t)(base + r16) * 64 + quad * 8;
    bf16x8 ha0 = *(const bf16x8*)(hr);
    bf16x8 ha1 = *(const bf16x8*)(hr + 32);
    bf16x8 ca0 = *(const bf16x8*)(&clds[wv * 16 + r16][quad * 8]);
    bf16x8 ca1 = *(const bf16x8*)(&clds[wv * 16 + r16][32 + quad * 8]);

    float isq4[4];
    if (!finalLayer) {
#pragma unroll
        for (int r = 0; r < 4; r++) isq4[r] = isq[base + quad * 4 + r];
    }

#pragma unroll
    for (int jt = 0; jt < 4; jt++) {
        const unsigned short* wr = wp + (size_t)(jt * 16 + r16) * 128 + quad * 8;
        const unsigned short* ar = aap + (size_t)(jt * 16 + r16) * 64 + quad * 8;
        const unsigned short* br = abp + (size_t)(jt * 16 + r16) * 64 + quad * 8;
        f32x4 P = {0.f, 0.f, 0.f, 0.f};
        f32x4 Q = {0.f, 0.f, 0.f, 0.f};
        f32x4 R = {0.f, 0.f, 0.f, 0.f};
        P = __builtin_amdgcn_mfma_f32_16x16x32_bf16(ha0, *(const bf16x8*)(wr), P, 0, 0, 0);
        P = __builtin_amdgcn_mfma_f32_16x16x32_bf16(ha1, *(const bf16x8*)(wr + 32), P, 0, 0, 0);
        P = __builtin_amdgcn_mfma_f32_16x16x32_bf16(ca0, *(const bf16x8*)(wr + 64), P, 0, 0, 0);
        P = __builtin_amdgcn_mfma_f32_16x16x32_bf16(ca1, *(const bf16x8*)(wr + 96), P, 0, 0, 0);
        Q = __builtin_amdgcn_mfma_f32_16x16x32_bf16(ha0, *(const bf16x8*)(ar), Q, 0, 0, 0);
        Q = __builtin_amdgcn_mfma_f32_16x16x32_bf16(ha1, *(const bf16x8*)(ar + 32), Q, 0, 0, 0);
        R = __builtin_amdgcn_mfma_f32_16x16x32_bf16(ha0, *(const bf16x8*)(br), R, 0, 0, 0);
        R = __builtin_amdgcn_mfma_f32_16x16x32_bf16(ha1, *(const bf16x8*)(br + 32), R, 0, 0, 0);
        int col = jt * 16 + r16;
#pragma unroll
        for (int r = 0; r < 4; r++) {
            int row = base + quad * 4 + r;
            float v = fmaxf(P[r] + Q[r] * R[r], 0.f);
            if (finalLayer) {
                outf[(size_t)row * 64 + col] = v;
            } else {
                outh[(size_t)row * 64 + col] = f2bf(v);
                outs[(size_t)row * 64 + col] = __float2half(v * isq4[r]);
            }
        }
    }
}

// ---------------------------------------------------------------------------
extern "C" void kernel_launch(void* const* d_in, const int* in_sizes, int n_in,
                              void* d_out, int out_size, void* d_ws, size_t ws_size,
                              hipStream_t stream) {
    const float* x = (const float*)d_in[0];
    const int* edges = (const int*)d_in[1];
    const float* W1 = (const float*)d_in[2];
    const float* b1 = (const float*)d_in[3];
    const float* W2 = (const float*)d_in[4];
    const float* A2a = (const float*)d_in[5];
    const float* A2b = (const float*)d_in[6];
    const float* W3 = (const float*)d_in[7];
    const float* A3a = (const float*)d_in[8];
    const float* A3b = (const float*)d_in[9];
    const float* W4 = (const float*)d_in[10];
    const float* A4a = (const float*)d_in[11];
    const float* A4b = (const float*)d_in[12];
    float* out = (float*)d_out;

    const int* src = edges;
    const int* dst = edges + N_EDGES;

    char* p = (char*)d_ws;
    auto alloc = [&](size_t bytes) {
        char* r = p;
        p += (bytes + 255) & ~(size_t)255;
        return r;
    };
    int* degi             = (int*)alloc(N_NODES * 4);
    int* incl             = (int*)alloc(N_NODES * 4);
    int* partial          = (int*)alloc(256 * 4);
    float* isq            = (float*)alloc(N_NODES * 4);
    int* rowptr           = (int*)alloc((N_NODES + 1) * 4);
    int* cursor           = (int*)alloc(N_NODES * 4);
    int* srcA             = (int*)alloc((N_EDGES + SRC_PAD) * 4);
    unsigned short* wpAll = (unsigned short*)alloc(W_TOTAL * 2);
    unsigned short* Ah    = (unsigned short*)alloc((size_t)N_NODES * 64 * 2);
    __half* As            = (__half*)alloc((size_t)N_NODES * 64 * 2);
    unsigned short* Bh    = (unsigned short*)alloc((size_t)N_NODES * 64 * 2);

    const unsigned short* W1p  = wpAll;
    const unsigned short* W2p  = wpAll + 8192;
    const unsigned short* A2ap = wpAll + 16384;
    const unsigned short* A2bp = wpAll + 20480;
    const unsigned short* W3p  = wpAll + 24576;
    const unsigned short* A3ap = wpAll + 32768;
    const unsigned short* A3bp = wpAll + 36864;
    const unsigned short* W4p  = wpAll + 40960;
    const unsigned short* A4ap = wpAll + 49152;
    const unsigned short* A4bp = wpAll + 53248;

    // ---- CSR build + weight pack ----
    hipMemsetAsync(degi, 0, N_NODES * 4, stream);
    count_pack_kernel<<<CLS_BLOCKS + WB, 256, 0, stream>>>(dst, degi, W1, W2, A2a, A2b,
                                                           W3, A3a, A3b, W4, A4a, A4b,
                                                           wpAll);
    scan1_kernel<<<SCAN_NB, 256, 0, stream>>>(degi, incl, partial, isq);
    scan2_kernel<<<1, 256, 0, stream>>>(partial, srcA);
    scan3_kernel<<<SCAN_NB, 256, 0, stream>>>(incl, partial, degi, rowptr, cursor);

    // ---- layer 1 (MFMA) + classed scatter, fused ----
    layer1_scatter<<<TB + CLS_BLOCKS, 256, 0, stream>>>(x, W1p, b1, isq, Ah, As,
                                                        src, dst, cursor, srcA);

    // ---- block 2: conv+dense fused (Ah -> Bh, As updated) ----
    conv_dense<<<FB, 256, 0, stream>>>(Ah, As, rowptr, srcA, isq, W2p, A2ap, A2bp,
                                       Bh, As, nullptr, 0);

    // ---- block 3: conv+dense fused (Bh -> Ah, As updated) ----
    conv_dense<<<FB, 256, 0, stream>>>(Bh, As, rowptr, srcA, isq, W3p, A3ap, A3bp,
                                       Ah, As, nullptr, 0);

    // ---- block 4: conv+dense fused -> d_out (fp32) ----
    conv_dense<<<FB, 256, 0, stream>>>(Ah, As, rowptr, srcA, isq, W4p, A4ap, A4bp,
                                       nullptr, nullptr, out, 1);
}

// Round 9
// 279.018 us; speedup vs baseline: 1.0808x; 1.0327x over previous
//
#include <hip/hip_runtime.h>
#include <hip/hip_bf16.h>
#include <hip/hip_fp16.h>

#define N_NODES 50000
#define N_EDGES 800000
#define NTILES 3125        // N_NODES / 16
#define SCAN_NB 196        // ceil(N_NODES / 256)
#define W_TOTAL 57344      // packed bf16 weight elements
#define WB 224             // weight-pack blocks
#define SRC_PAD 512        // sentinel tail on srcA
#define CLS_BLOCKS 1024    // classed edge-walk blocks
#define CLS_STRIDE (128 * 256)
#define CLS_RANGE 6250     // dst nodes per class (8 * 6250 = 50000)
#define TB 782             // layer1 MFMA blocks (4 waves each)
#define FB 782             // fused conv+dense blocks (64 rows each)

typedef __attribute__((ext_vector_type(8))) short bf16x8;          // MFMA A/B frag
typedef __attribute__((ext_vector_type(4))) float f32x4;           // MFMA C/D frag
typedef __attribute__((ext_vector_type(8))) unsigned short u16x8;  // 16B store

__device__ inline unsigned short f2bf(float f) {  // round-to-nearest-even
    unsigned int x = __float_as_uint(f);
    unsigned int r = (x + 0x7FFF + ((x >> 16) & 1)) >> 16;
    return (unsigned short)r;
}
__device__ inline float2 h2f2(unsigned int u) {   // packed half2 -> float2
    __half2 h = *(__half2*)&u;
    return make_float2(__low2float(h), __high2float(h));
}

// ---------------------------------------------------------------------------
// fused: XCD-classed degree count (blocks [0,CLS_BLOCKS)) + weight pack (rest).
__global__ __launch_bounds__(256) void count_pack_kernel(
    const int* __restrict__ dst, int* __restrict__ degi,
    const float* W1, const float* W2, const float* A2a, const float* A2b,
    const float* W3, const float* A3a, const float* A3b,
    const float* W4, const float* A4a, const float* A4b,
    unsigned short* __restrict__ wp) {
    if (blockIdx.x < CLS_BLOCKS) {
        int cls = blockIdx.x & 7;
        int k = blockIdx.x >> 3;
        int lo = cls * CLS_RANGE, hi = lo + CLS_RANGE;
        for (int e = k * 256 + (int)threadIdx.x; e < N_EDGES; e += CLS_STRIDE) {
            int d = dst[e];
            if (d >= lo && d < hi) atomicAdd(&degi[d], 1);
        }
    } else {
        int i = (blockIdx.x - CLS_BLOCKS) * 256 + threadIdx.x;
        if (i >= W_TOTAL) return;
        float v;
        if (i < 8192)       v = W1[i];
        else if (i < 16384) v = W2[i - 8192];
        else if (i < 20480) v = A2a[i - 16384];
        else if (i < 24576) v = A2b[i - 20480];
        else if (i < 32768) v = W3[i - 24576];
        else if (i < 36864) v = A3a[i - 32768];
        else if (i < 40960) v = A3b[i - 36864];
        else if (i < 49152) v = W4[i - 40960];
        else if (i < 53248) v = A4a[i - 49152];
        else                v = A4b[i - 53248];
        wp[i] = f2bf(v);
    }
}

// scan phase 1: per-256-chunk inclusive scan + chunk totals; isq = rsqrt(max(deg,1))
__global__ __launch_bounds__(256) void scan1_kernel(const int* __restrict__ degi,
                                                    int* __restrict__ incl,
                                                    int* __restrict__ partial,
                                                    float* __restrict__ isq) {
    __shared__ int s[256];
    int tid = threadIdx.x;
    int gid = blockIdx.x * 256 + tid;
    int v = (gid < N_NODES) ? degi[gid] : 0;
    if (gid < N_NODES) isq[gid] = rsqrtf(fmaxf((float)v, 1.0f));
    s[tid] = v;
    __syncthreads();
    for (int off = 1; off < 256; off <<= 1) {
        int t = (tid >= off) ? s[tid - off] : 0;
        __syncthreads();
        s[tid] += t;
        __syncthreads();
    }
    if (gid < N_NODES) incl[gid] = s[tid];
    if (tid == 255) partial[blockIdx.x] = s[255];
}

// scan phase 2 (one block): exclusive scan of chunk totals + srcA sentinel init
__global__ __launch_bounds__(256) void scan2_kernel(int* __restrict__ partial,
                                                    unsigned short* __restrict__ srcA) {
    __shared__ int s[256];
    int tid = threadIdx.x;
    int v = (tid < SCAN_NB) ? partial[tid] : 0;
    s[tid] = v;
    __syncthreads();
    for (int off = 1; off < 256; off <<= 1) {
        int t = (tid >= off) ? s[tid - off] : 0;
        __syncthreads();
        s[tid] += t;
        __syncthreads();
    }
    if (tid < SCAN_NB) partial[tid] = s[tid] - v;  // exclusive
    srcA[N_EDGES + tid] = 0;                       // sentinel tail (node 0)
    srcA[N_EDGES + 256 + tid] = 0;
}

// scan phase 3: rowptr (exclusive) + cursor copy
__global__ __launch_bounds__(256) void scan3_kernel(const int* __restrict__ incl,
                                                    const int* __restrict__ partial,
                                                    const int* __restrict__ degi,
                                                    int* __restrict__ rowptr,
                                                    int* __restrict__ cursor) {
    int gid = blockIdx.x * 256 + threadIdx.x;
    if (gid < N_NODES) {
        int excl = partial[blockIdx.x] + incl[gid] - degi[gid];
        rowptr[gid] = excl;
        cursor[gid] = excl;
    }
    if (gid == 0) rowptr[N_NODES] = N_EDGES;
}

// ---------------------------------------------------------------------------
// fused layer1 + classed scatter (srcA entries are ushort: src < 50000 < 65536).
__global__ __launch_bounds__(256) void layer1_scatter(const float* __restrict__ x,
                                                      const unsigned short* __restrict__ w1p,
                                                      const float* __restrict__ b1,
                                                      const float* __restrict__ isq,
                                                      unsigned short* __restrict__ outh,
                                                      __half* __restrict__ outs,
                                                      const int* __restrict__ src,
                                                      const int* __restrict__ dst,
                                                      int* __restrict__ cursor,
                                                      unsigned short* __restrict__ srcA) {
    if (blockIdx.x >= TB) {
        int cb = blockIdx.x - TB;
        int cls = cb & 7;
        int k = cb >> 3;
        int lo = cls * CLS_RANGE, hi = lo + CLS_RANGE;
        for (int e = k * 256 + (int)threadIdx.x; e < N_EDGES; e += CLS_STRIDE) {
            int d = dst[e];
            if (d >= lo && d < hi) {
                int pos = atomicAdd(&cursor[d], 1);
                srcA[pos] = (unsigned short)src[e];
            }
        }
        return;
    }

    int wave = (blockIdx.x * 256 + threadIdx.x) >> 6;
    if (wave >= NTILES) return;
    int lane = threadIdx.x & 63;
    int r16 = lane & 15, quad = lane >> 4;
    int base = wave * 16;

    bf16x8 a[4];
    const float* xr = x + (size_t)(base + r16) * 128 + quad * 8;
#pragma unroll
    for (int kb = 0; kb < 4; kb++) {
        float4 f0 = *(const float4*)(xr + kb * 32);
        float4 f1 = *(const float4*)(xr + kb * 32 + 4);
        bf16x8 v;
        v[0] = (short)f2bf(f0.x); v[1] = (short)f2bf(f0.y);
        v[2] = (short)f2bf(f0.z); v[3] = (short)f2bf(f0.w);
        v[4] = (short)f2bf(f1.x); v[5] = (short)f2bf(f1.y);
        v[6] = (short)f2bf(f1.z); v[7] = (short)f2bf(f1.w);
        a[kb] = v;
    }

    float isq4[4];
#pragma unroll
    for (int r = 0; r < 4; r++) isq4[r] = isq[base + quad * 4 + r];

#pragma unroll
    for (int jt = 0; jt < 4; jt++) {
        f32x4 acc = {0.f, 0.f, 0.f, 0.f};
        const unsigned short* wr = w1p + (size_t)(jt * 16 + r16) * 128 + quad * 8;
#pragma unroll
        for (int kb = 0; kb < 4; kb++) {
            bf16x8 b = *(const bf16x8*)(wr + kb * 32);
            acc = __builtin_amdgcn_mfma_f32_16x16x32_bf16(a[kb], b, acc, 0, 0, 0);
        }
        int col = jt * 16 + r16;
        float bias = b1[col];
#pragma unroll
        for (int r = 0; r < 4; r++) {
            int row = base + quad * 4 + r;
            float v = fmaxf(acc[r] + bias, 0.f);
            outh[(size_t)row * 64 + col] = f2bf(v);
            outs[(size_t)row * 64 + col] = __float2half(v * isq4[r]);
        }
    }
}

// ---------------------------------------------------------------------------
// FUSED conv + dense, one block = 64 rows (4 MFMA tiles).
// Phase 1 (conv): wave wv computes conv for rows [wv*16, wv*16+16) in 2 groups
//   of 8 rows (8 feat-lanes x uint4 = 16B gather -> one instr serves 8 edges);
//   result -> LDS bf16 [64][64].
// Phase 2 (dense): wave wv runs MFMA tile wv; conv A-frags from LDS.
// hs_in / hs_out are DISTINCT buffers (ping-pong) -- phase-2 writes must not
// race other blocks' phase-1 gathers (inter-block order undefined).
__global__ __launch_bounds__(256) void conv_dense(const unsigned short* __restrict__ h,
                                                  const __half* __restrict__ hs,
                                                  const int* __restrict__ rowptr,
                                                  const unsigned short* __restrict__ srcA,
                                                  const float* __restrict__ isq,
                                                  const unsigned short* __restrict__ wp,
                                                  const unsigned short* __restrict__ aap,
                                                  const unsigned short* __restrict__ abp,
                                                  unsigned short* __restrict__ outh,
                                                  __half* __restrict__ outs,
                                                  float* __restrict__ outf,
                                                  int finalLayer) {
    __shared__ unsigned short clds[64][64];   // conv result (bf16), 8 KB

    int tid = threadIdx.x;
    int wv = tid >> 6;
    int lane = tid & 63;
    int blockBase = blockIdx.x * 64;

    // ---- phase 1: conv for this block's 64 rows ----
    {
        int e8 = lane >> 3, fl = lane & 7;
        const unsigned int* hsp = (const unsigned int*)hs;  // hs row = 32 uints
#pragma unroll
        for (int g = 0; g < 2; g++) {
            int lrow = wv * 16 + g * 8 + e8;
            int row = blockBase + lrow;
            if (row < N_NODES) {
                int b = rowptr[row];
                int cnt = rowptr[row + 1] - b;
                float acc[8];
#pragma unroll
                for (int k = 0; k < 8; k++) acc[k] = 0.f;
                for (int i = 0; i < cnt; i += 4) {
#pragma unroll
                    for (int u = 0; u < 4; u++) {
                        int j = i + u;
                        int s = srcA[b + j];                 // sentinel-safe
                        uint4 raw = *(const uint4*)(hsp + (size_t)s * 32 + fl * 4);
                        unsigned int msk = (j < cnt) ? 0xFFFFFFFFu : 0u;
                        float2 f0 = h2f2(raw.x & msk);
                        float2 f1 = h2f2(raw.y & msk);
                        float2 f2 = h2f2(raw.z & msk);
                        float2 f3 = h2f2(raw.w & msk);
                        acc[0] += f0.x; acc[1] += f0.y; acc[2] += f1.x; acc[3] += f1.y;
                        acc[4] += f2.x; acc[5] += f2.y; acc[6] += f3.x; acc[7] += f3.y;
                    }
                }
                float sc = isq[row];
                u16x8 o;
#pragma unroll
                for (int k = 0; k < 8; k++) o[k] = f2bf(acc[k] * sc);
                *(u16x8*)(&clds[lrow][fl * 8]) = o;
            }
        }
    }
    __syncthreads();

    // ---- phase 2: dense MFMA tile wv (16 rows) ----
    int r16 = lane & 15, quad = lane >> 4;
    int base = blockBase + wv * 16;
    if (base >= N_NODES) return;

    const unsigned short* hr = h + (size_t)(base + r16) * 64 + quad * 8;
    bf16x8 ha0 = *(const bf16x8*)(hr);
    bf16x8 ha1 = *(const bf16x8*)(hr + 32);
    bf16x8 ca0 = *(const bf16x8*)(&clds[wv * 16 + r16][quad * 8]);
    bf16x8 ca1 = *(const bf16x8*)(&clds[wv * 16 + r16][32 + quad * 8]);

    float isq4[4];
    if (!finalLayer) {
#pragma unroll
        for (int r = 0; r < 4; r++) isq4[r] = isq[base + quad * 4 + r];
    }

#pragma unroll
    for (int jt = 0; jt < 4; jt++) {
        const unsigned short* wr = wp + (size_t)(jt * 16 + r16) * 128 + quad * 8;
        const unsigned short* ar = aap + (size_t)(jt * 16 + r16) * 64 + quad * 8;
        const unsigned short* br = abp + (size_t)(jt * 16 + r16) * 64 + quad * 8;
        f32x4 P = {0.f, 0.f, 0.f, 0.f};
        f32x4 Q = {0.f, 0.f, 0.f, 0.f};
        f32x4 R = {0.f, 0.f, 0.f, 0.f};
        P = __builtin_amdgcn_mfma_f32_16x16x32_bf16(ha0, *(const bf16x8*)(wr), P, 0, 0, 0);
        P = __builtin_amdgcn_mfma_f32_16x16x32_bf16(ha1, *(const bf16x8*)(wr + 32), P, 0, 0, 0);
        P = __builtin_amdgcn_mfma_f32_16x16x32_bf16(ca0, *(const bf16x8*)(wr + 64), P, 0, 0, 0);
        P = __builtin_amdgcn_mfma_f32_16x16x32_bf16(ca1, *(const bf16x8*)(wr + 96), P, 0, 0, 0);
        Q = __builtin_amdgcn_mfma_f32_16x16x32_bf16(ha0, *(const bf16x8*)(ar), Q, 0, 0, 0);
        Q = __builtin_amdgcn_mfma_f32_16x16x32_bf16(ha1, *(const bf16x8*)(ar + 32), Q, 0, 0, 0);
        R = __builtin_amdgcn_mfma_f32_16x16x32_bf16(ha0, *(const bf16x8*)(br), R, 0, 0, 0);
        R = __builtin_amdgcn_mfma_f32_16x16x32_bf16(ha1, *(const bf16x8*)(br + 32), R, 0, 0, 0);
        int col = jt * 16 + r16;
#pragma unroll
        for (int r = 0; r < 4; r++) {
            int row = base + quad * 4 + r;
            float v = fmaxf(P[r] + Q[r] * R[r], 0.f);
            if (finalLayer) {
                outf[(size_t)row * 64 + col] = v;
            } else {
                outh[(size_t)row * 64 + col] = f2bf(v);
                outs[(size_t)row * 64 + col] = __float2half(v * isq4[r]);
            }
        }
    }
}

// ---------------------------------------------------------------------------
extern "C" void kernel_launch(void* const* d_in, const int* in_sizes, int n_in,
                              void* d_out, int out_size, void* d_ws, size_t ws_size,
                              hipStream_t stream) {
    const float* x = (const float*)d_in[0];
    const int* edges = (const int*)d_in[1];
    const float* W1 = (const float*)d_in[2];
    const float* b1 = (const float*)d_in[3];
    const float* W2 = (const float*)d_in[4];
    const float* A2a = (const float*)d_in[5];
    const float* A2b = (const float*)d_in[6];
    const float* W3 = (const float*)d_in[7];
    const float* A3a = (const float*)d_in[8];
    const float* A3b = (const float*)d_in[9];
    const float* W4 = (const float*)d_in[10];
    const float* A4a = (const float*)d_in[11];
    const float* A4b = (const float*)d_in[12];
    float* out = (float*)d_out;

    const int* src = edges;
    const int* dst = edges + N_EDGES;

    char* p = (char*)d_ws;
    auto alloc = [&](size_t bytes) {
        char* r = p;
        p += (bytes + 255) & ~(size_t)255;
        return r;
    };
    int* degi             = (int*)alloc(N_NODES * 4);
    int* incl             = (int*)alloc(N_NODES * 4);
    int* partial          = (int*)alloc(256 * 4);
    float* isq            = (float*)alloc(N_NODES * 4);
    int* rowptr           = (int*)alloc((N_NODES + 1) * 4);
    int* cursor           = (int*)alloc(N_NODES * 4);
    unsigned short* srcA  = (unsigned short*)alloc((N_EDGES + SRC_PAD) * 2);
    unsigned short* wpAll = (unsigned short*)alloc(W_TOTAL * 2);
    unsigned short* Ah    = (unsigned short*)alloc((size_t)N_NODES * 64 * 2);
    __half* As            = (__half*)alloc((size_t)N_NODES * 64 * 2);
    unsigned short* Bh    = (unsigned short*)alloc((size_t)N_NODES * 64 * 2);
    __half* Bs            = (__half*)alloc((size_t)N_NODES * 64 * 2);

    const unsigned short* W1p  = wpAll;
    const unsigned short* W2p  = wpAll + 8192;
    const unsigned short* A2ap = wpAll + 16384;
    const unsigned short* A2bp = wpAll + 20480;
    const unsigned short* W3p  = wpAll + 24576;
    const unsigned short* A3ap = wpAll + 32768;
    const unsigned short* A3bp = wpAll + 36864;
    const unsigned short* W4p  = wpAll + 40960;
    const unsigned short* A4ap = wpAll + 49152;
    const unsigned short* A4bp = wpAll + 53248;

    // ---- CSR build + weight pack ----
    hipMemsetAsync(degi, 0, N_NODES * 4, stream);
    count_pack_kernel<<<CLS_BLOCKS + WB, 256, 0, stream>>>(dst, degi, W1, W2, A2a, A2b,
                                                           W3, A3a, A3b, W4, A4a, A4b,
                                                           wpAll);
    scan1_kernel<<<SCAN_NB, 256, 0, stream>>>(degi, incl, partial, isq);
    scan2_kernel<<<1, 256, 0, stream>>>(partial, srcA);
    scan3_kernel<<<SCAN_NB, 256, 0, stream>>>(incl, partial, degi, rowptr, cursor);

    // ---- layer 1 (MFMA) + classed scatter, fused ----
    layer1_scatter<<<TB + CLS_BLOCKS, 256, 0, stream>>>(x, W1p, b1, isq, Ah, As,
                                                        src, dst, cursor, srcA);

    // ---- block 2: conv+dense fused (Ah,As -> Bh,Bs) ----
    conv_dense<<<FB, 256, 0, stream>>>(Ah, As, rowptr, srcA, isq, W2p, A2ap, A2bp,
                                       Bh, Bs, nullptr, 0);

    // ---- block 3: conv+dense fused (Bh,Bs -> Ah,As) ----
    conv_dense<<<FB, 256, 0, stream>>>(Bh, Bs, rowptr, srcA, isq, W3p, A3ap, A3bp,
                                       Ah, As, nullptr, 0);

    // ---- block 4: conv+dense fused -> d_out (fp32) ----
    conv_dense<<<FB, 256, 0, stream>>>(Ah, As, rowptr, srcA, isq, W4p, A4ap, A4bp,
                                       nullptr, nullptr, out, 1);
}